// Round 1
// baseline (808.861 us; speedup 1.0000x reference)
//
#include <hip/hip_runtime.h>

// Problem constants (from reference): H=W=1024, T=16 transforms, 20 iterations.
constexpr int W = 1024;
constexpr int H = 1024;
constexpr int T = 16;
constexpr int ITERS = 20;

// coef layout: per transform t, 8 floats: {p, Ax, Bx, Cx, Ay, By, Cy, pad}
__global__ void setup_coef(const float* __restrict__ theta,
                           const float* __restrict__ probs,
                           float* __restrict__ coef) {
    int t = threadIdx.x;
    if (t >= T) return;
    float sum = 0.f;
    for (int i = 0; i < T; ++i) sum += probs[i];
    float p = probs[t] / sum;
    const float* th = theta + 6 * t;
    float a = th[0], b = th[1], c = th[2];
    float d = th[3], e = th[4], f = th[5];
    // ix = (gx+1)*(W/2) - 0.5, gx = a*xs + b*ys + c, xs=(2w+1)/W-1, ys=(2h+1)/H-1
    // With H==W: ix = a*w + b*h + Cx ; iy = d*w + e*h + Cy
    float Cx = a * ((1.0f - (float)W) * 0.5f)
             + b * ((1.0f - (float)H) * 0.5f)
             + (c + 1.0f) * ((float)W * 0.5f) - 0.5f;
    float Cy = d * ((1.0f - (float)W) * 0.5f)
             + e * ((1.0f - (float)H) * 0.5f)
             + (f + 1.0f) * ((float)H * 0.5f) - 0.5f;
    float* o = coef + 8 * t;
    o[0] = p;  o[1] = a;  o[2] = b;  o[3] = Cx;
    o[4] = d;  o[5] = e;  o[6] = Cy; o[7] = 0.f;
}

__global__ __launch_bounds__(256) void ifs_iter(const float* __restrict__ in,
                                                float* __restrict__ out,
                                                const float* __restrict__ coef,
                                                const float* __restrict__ base,
                                                int add_base) {
    __shared__ float sc[T * 8];
    int lid = threadIdx.y * 64 + threadIdx.x;
    if (lid < T * 8) sc[lid] = coef[lid];
    __syncthreads();

    int w = blockIdx.x * 64 + threadIdx.x;
    int h = blockIdx.y * 4 + threadIdx.y;
    float wf = (float)w, hf = (float)h;

    // tile bounds for the uniform bbox skip
    float w0 = (float)(blockIdx.x * 64), w1 = w0 + 63.f;
    float h0 = (float)(blockIdx.y * 4),  h1 = h0 + 3.f;

    float acc = 0.f;

#pragma unroll
    for (int t = 0; t < T; ++t) {
        float p  = sc[t * 8 + 0];
        float Ax = sc[t * 8 + 1], Bx = sc[t * 8 + 2], Cx = sc[t * 8 + 3];
        float Ay = sc[t * 8 + 4], By = sc[t * 8 + 5], Cy = sc[t * 8 + 6];

        // interval bbox of (ix, iy) over this block's tile — uniform branch
        float ixmin = Cx + (Ax >= 0.f ? Ax * w0 : Ax * w1) + (Bx >= 0.f ? Bx * h0 : Bx * h1);
        float ixmax = Cx + (Ax >= 0.f ? Ax * w1 : Ax * w0) + (Bx >= 0.f ? Bx * h1 : Bx * h0);
        float iymin = Cy + (Ay >= 0.f ? Ay * w0 : Ay * w1) + (By >= 0.f ? By * h0 : By * h1);
        float iymax = Cy + (Ay >= 0.f ? Ay * w1 : Ay * w0) + (By >= 0.f ? By * h1 : By * h0);
        if (ixmax <= -1.f || ixmin >= (float)W || iymax <= -1.f || iymin >= (float)H)
            continue;  // entire tile contributes exactly 0 for this transform

        float ix = Ax * wf + Bx * hf + Cx;
        float iy = Ay * wf + By * hf + Cy;

        // possibly-nonzero iff ix in (-1, W) and iy in (-1, H)
        if (ix > -1.f && ix < (float)W && iy > -1.f && iy < (float)H) {
            float x0f = floorf(ix), y0f = floorf(iy);
            int x0 = (int)x0f, y0 = (int)y0f;      // x0 in [-1, W-1], y0 in [-1, H-1]
            float wx1 = ix - x0f, wy1 = iy - y0f;
            float wx0 = 1.f - wx1, wy0 = 1.f - wy1;

            bool vx0 = (x0 >= 0);
            bool vx1 = (x0 < W - 1);
            bool vy0 = (y0 >= 0);
            bool vy1 = (y0 < H - 1);

            int xc0 = max(x0, 0), xc1 = min(x0 + 1, W - 1);
            int yc0 = max(y0, 0), yc1 = min(y0 + 1, H - 1);

            const float* r0 = in + yc0 * W;
            const float* r1 = in + yc1 * W;
            float v00 = (vy0 && vx0) ? r0[xc0] : 0.f;
            float v01 = (vy0 && vx1) ? r0[xc1] : 0.f;
            float v10 = (vy1 && vx0) ? r1[xc0] : 0.f;
            float v11 = (vy1 && vx1) ? r1[xc1] : 0.f;

            acc += p * (wy0 * (wx0 * v00 + wx1 * v01) +
                        wy1 * (wx0 * v10 + wx1 * v11));
        }
    }

    if (add_base) acc += base[0];
    out[h * W + w] = acc;
}

extern "C" void kernel_launch(void* const* d_in, const int* in_sizes, int n_in,
                              void* d_out, int out_size, void* d_ws, size_t ws_size,
                              hipStream_t stream) {
    const float* canvas0 = (const float*)d_in[0];
    const float* theta   = (const float*)d_in[1];
    const float* probs   = (const float*)d_in[2];
    const float* base    = (const float*)d_in[3];
    float* out = (float*)d_out;

    float* bufA = (float*)d_ws;           // 4 MB ping buffer
    float* coef = bufA + (size_t)W * H;   // 128 floats of coefficients

    setup_coef<<<1, 64, 0, stream>>>(theta, probs, coef);

    dim3 block(64, 4);
    dim3 grid(W / 64, H / 4);

    // ping-pong: even iters write bufA, odd iters write d_out; iter 19 (odd) -> d_out
    const float* cur = canvas0;
    for (int i = 0; i < ITERS; ++i) {
        float* dst = (i & 1) ? out : bufA;
        int add_base = (i == ITERS - 1) ? 1 : 0;
        ifs_iter<<<grid, block, 0, stream>>>(cur, dst, coef, base, add_base);
        cur = dst;
    }
}

// Round 2
// 562.817 us; speedup vs baseline: 1.4372x; 1.4372x over previous
//
#include <hip/hip_runtime.h>

// H=W=1024, T=16 transforms, 20 iterations. Intermediates live in two
// zero-bordered padded buffers: PH rows x PITCH floats, pixel (h,w) at
// [(h+1)*PITCH + (w+1)]. Border rows/cols are zero => bilinear corners of any
// in-range sample are unconditionally loadable (zeros padding is exact).
constexpr int W = 1024;
constexpr int H = 1024;
constexpr int T = 16;
constexpr int ITERS = 20;
constexpr int PITCH = 1040;           // floats; 4160 B, 64B-aligned rows
constexpr int PH = H + 2;             // 1026 rows
constexpr int PAD_ELEMS = PH * PITCH; // 1,067,040 floats per buffer

// coef per transform t: {p, Ax, Bx, Cxp, Ay, By, Cyp, 0} — Cxp/Cyp include the
// +1 pad shift, so ixp = Ax*w + Bx*h + Cxp is the PADDED x coordinate.
__global__ void setup_coef(const float* __restrict__ theta,
                           const float* __restrict__ probs,
                           float* __restrict__ coef) {
    int t = threadIdx.x;
    if (t >= T) return;
    float sum = 0.f;
    for (int i = 0; i < T; ++i) sum += probs[i];
    float p = probs[t] / sum;
    const float* th = theta + 6 * t;
    float a = th[0], b = th[1], c = th[2];
    float d = th[3], e = th[4], f = th[5];
    float Cx = a * ((1.0f - (float)W) * 0.5f)
             + b * ((1.0f - (float)H) * 0.5f)
             + (c + 1.0f) * ((float)W * 0.5f) - 0.5f;
    float Cy = d * ((1.0f - (float)W) * 0.5f)
             + e * ((1.0f - (float)H) * 0.5f)
             + (f + 1.0f) * ((float)H * 0.5f) - 0.5f;
    float* o = coef + 8 * t;
    o[0] = p;  o[1] = a;  o[2] = b;  o[3] = Cx + 1.0f;
    o[4] = d;  o[5] = e;  o[6] = Cy + 1.0f; o[7] = 0.f;
}

__global__ __launch_bounds__(256) void copy_in(const float* __restrict__ src,
                                               float* __restrict__ dst) {
    int i = blockIdx.x * 256 + threadIdx.x;   // i in [0, H*W)
    int h = i >> 10, w = i & 1023;
    dst[(h + 1) * PITCH + (w + 1)] = src[i];
}

__global__ __launch_bounds__(256) void ifs_iter(const float* __restrict__ in,
                                                float* __restrict__ out,
                                                const float* __restrict__ coef,
                                                const float* __restrict__ base,
                                                int dstPitch, int dstOff,
                                                int add_base) {
    __shared__ float sc[T * 8];
    int lid = threadIdx.y * 64 + threadIdx.x;
    if (lid < T * 8) sc[lid] = coef[lid];
    __syncthreads();

    int w = blockIdx.x * 64 + threadIdx.x;
    int h = blockIdx.y * 4 + threadIdx.y;
    float wf = (float)w, hf = (float)h;

    // tile bounds for the uniform bbox skip (padded coords)
    float w0 = (float)(blockIdx.x * 64), w1 = w0 + 63.f;
    float h0 = (float)(blockIdx.y * 4),  h1 = h0 + 3.f;

    float acc = 0.f;

#pragma unroll
    for (int t = 0; t < T; ++t) {
        float p  = sc[t * 8 + 0];
        float Ax = sc[t * 8 + 1], Bx = sc[t * 8 + 2], Cx = sc[t * 8 + 3];
        float Ay = sc[t * 8 + 4], By = sc[t * 8 + 5], Cy = sc[t * 8 + 6];

        // interval bbox over this tile; sample can contribute iff
        // ixp in (0, W+1) and iyp in (0, H+1)
        float ixmin = Cx + (Ax >= 0.f ? Ax * w0 : Ax * w1) + (Bx >= 0.f ? Bx * h0 : Bx * h1);
        float ixmax = Cx + (Ax >= 0.f ? Ax * w1 : Ax * w0) + (Bx >= 0.f ? Bx * h1 : Bx * h0);
        float iymin = Cy + (Ay >= 0.f ? Ay * w0 : Ay * w1) + (By >= 0.f ? By * h0 : By * h1);
        float iymax = Cy + (Ay >= 0.f ? Ay * w1 : Ay * w0) + (By >= 0.f ? By * h1 : By * h0);
        if (ixmax <= 0.f || ixmin >= (float)(W + 1) || iymax <= 0.f || iymin >= (float)(H + 1))
            continue;

        float ixp = fmaf(Ax, wf, fmaf(Bx, hf, Cx));
        float iyp = fmaf(Ay, wf, fmaf(By, hf, Cy));
        float xf = floorf(ixp), yf = floorf(iyp);
        float wx1 = ixp - xf, wy1 = iyp - yf;
        int x0 = (int)xf, y0 = (int)yf;
        // active iff x0 in [0,W] and y0 in [0,H]; then all 4 corners are
        // in-bounds of the padded buffer (border rows/cols are zero).
        bool act = ((unsigned)x0 <= (unsigned)W) && ((unsigned)y0 <= (unsigned)H);
        unsigned idx = (unsigned)y0 * (unsigned)PITCH + (unsigned)x0;
        idx = act ? idx : 0u;          // safe address for inactive lanes
        float pe = act ? p : 0.f;      // zero contribution for inactive lanes

        const float* q = in + idx;
        float v00 = q[0];
        float v01 = q[1];
        float v10 = q[PITCH];
        float v11 = q[PITCH + 1];
        float top = fmaf(wx1, v01 - v00, v00);
        float bot = fmaf(wx1, v11 - v10, v10);
        float val = fmaf(wy1, bot - top, top);
        acc = fmaf(pe, val, acc);
    }

    if (add_base) acc += base[0];
    out[h * dstPitch + w + dstOff] = acc;
}

extern "C" void kernel_launch(void* const* d_in, const int* in_sizes, int n_in,
                              void* d_out, int out_size, void* d_ws, size_t ws_size,
                              hipStream_t stream) {
    const float* canvas0 = (const float*)d_in[0];
    const float* theta   = (const float*)d_in[1];
    const float* probs   = (const float*)d_in[2];
    const float* base    = (const float*)d_in[3];
    float* out = (float*)d_out;

    float* bufA = (float*)d_ws;
    float* bufB = bufA + PAD_ELEMS;
    float* coef = bufB + PAD_ELEMS;

    // zero both padded buffers (borders must be 0; also kills 0xAA poison)
    hipMemsetAsync(d_ws, 0, (size_t)2 * PAD_ELEMS * sizeof(float), stream);

    setup_coef<<<1, 64, 0, stream>>>(theta, probs, coef);
    copy_in<<<(H * W) / 256, 256, 0, stream>>>(canvas0, bufA);

    dim3 block(64, 4);
    dim3 grid(W / 64, H / 4);

    const float* cur = bufA;
    for (int i = 0; i < ITERS; ++i) {
        bool last = (i == ITERS - 1);
        float* dst = last ? out : ((i & 1) ? bufA : bufB);
        int dstPitch = last ? W : PITCH;
        int dstOff   = last ? 0 : (PITCH + 1);
        ifs_iter<<<grid, block, 0, stream>>>(cur, dst, coef, base,
                                             dstPitch, dstOff, last ? 1 : 0);
        cur = dst;
    }
}

// Round 3
// 532.149 us; speedup vs baseline: 1.5200x; 1.0576x over previous
//
#include <hip/hip_runtime.h>

// H=W=1024, T=16, 20 iterations. Intermediates in two zero-bordered padded
// buffers: PH x PITCH floats, pixel (h,w) at [(h+1)*PITCH + (w+1)]. Zero
// borders => all 4 bilinear corners of any in-range sample are loadable
// unconditionally (zeros padding is exact).
//
// Wave mapping: each 64-lane wave covers an 8x8 pixel patch (not 64x1) so a
// gather instruction's 64 addresses span ~8(|Ay|+|By|) rows instead of
// ~64|Ay| -> far fewer distinct cache lines per TCP request for random
// affine transforms. Block = 4 waves in 2x2 -> 16x16 pixel tile.
constexpr int W = 1024;
constexpr int H = 1024;
constexpr int T = 16;
constexpr int ITERS = 20;
constexpr int PITCH = 1040;           // floats; 4160 B rows
constexpr int PH = H + 2;             // 1026 rows
constexpr int PAD_ELEMS = PH * PITCH;

// coef per transform t: {p, Ax, Bx, Cxp, Ay, By, Cyp, 0}; Cxp/Cyp include the
// +1 pad shift, so ixp = Ax*w + Bx*h + Cxp is the PADDED x coordinate.
__global__ void setup_coef(const float* __restrict__ theta,
                           const float* __restrict__ probs,
                           float* __restrict__ coef) {
    int t = threadIdx.x;
    if (t >= T) return;
    float sum = 0.f;
    for (int i = 0; i < T; ++i) sum += probs[i];
    float p = probs[t] / sum;
    const float* th = theta + 6 * t;
    float a = th[0], b = th[1], c = th[2];
    float d = th[3], e = th[4], f = th[5];
    float Cx = a * ((1.0f - (float)W) * 0.5f)
             + b * ((1.0f - (float)H) * 0.5f)
             + (c + 1.0f) * ((float)W * 0.5f) - 0.5f;
    float Cy = d * ((1.0f - (float)W) * 0.5f)
             + e * ((1.0f - (float)H) * 0.5f)
             + (f + 1.0f) * ((float)H * 0.5f) - 0.5f;
    float* o = coef + 8 * t;
    o[0] = p;  o[1] = a;  o[2] = b;  o[3] = Cx + 1.0f;
    o[4] = d;  o[5] = e;  o[6] = Cy + 1.0f; o[7] = 0.f;
}

__global__ __launch_bounds__(256) void copy_in(const float* __restrict__ src,
                                               float* __restrict__ dst) {
    int i = blockIdx.x * 256 + threadIdx.x;   // i in [0, H*W)
    int h = i >> 10, w = i & 1023;
    dst[(h + 1) * PITCH + (w + 1)] = src[i];
}

__global__ __launch_bounds__(256) void ifs_iter(const float* __restrict__ in,
                                                float* __restrict__ out,
                                                const float* __restrict__ coef,
                                                const float* __restrict__ base,
                                                int dstPitch, int dstOff,
                                                int add_base) {
    __shared__ float sc[T * 8];
    int lid = threadIdx.x;
    if (lid < T * 8) sc[lid] = coef[lid];
    __syncthreads();

    // 8x8-per-wave mapping; 4 waves tile a 16x16 pixel block.
    int lane = lid & 63;
    int wv   = lid >> 6;
    int w = blockIdx.x * 16 + ((wv & 1) << 3) + (lane & 7);
    int h = blockIdx.y * 16 + ((wv >> 1) << 3) + (lane >> 3);
    float wf = (float)w, hf = (float)h;

    // tile bounds for the uniform bbox skip (padded coords)
    float w0 = (float)(blockIdx.x * 16), w1 = w0 + 15.f;
    float h0 = (float)(blockIdx.y * 16), h1 = h0 + 15.f;

    float acc = 0.f;

#pragma unroll
    for (int t = 0; t < T; ++t) {
        float p  = sc[t * 8 + 0];
        float Ax = sc[t * 8 + 1], Bx = sc[t * 8 + 2], Cx = sc[t * 8 + 3];
        float Ay = sc[t * 8 + 4], By = sc[t * 8 + 5], Cy = sc[t * 8 + 6];

        // interval bbox over this tile; sample can contribute iff
        // ixp in (0, W+1) and iyp in (0, H+1)
        float ixmin = Cx + (Ax >= 0.f ? Ax * w0 : Ax * w1) + (Bx >= 0.f ? Bx * h0 : Bx * h1);
        float ixmax = Cx + (Ax >= 0.f ? Ax * w1 : Ax * w0) + (Bx >= 0.f ? Bx * h1 : Bx * h0);
        float iymin = Cy + (Ay >= 0.f ? Ay * w0 : Ay * w1) + (By >= 0.f ? By * h0 : By * h1);
        float iymax = Cy + (Ay >= 0.f ? Ay * w1 : Ay * w0) + (By >= 0.f ? By * h1 : By * h0);
        if (ixmax <= 0.f || ixmin >= (float)(W + 1) || iymax <= 0.f || iymin >= (float)(H + 1))
            continue;

        float ixp = fmaf(Ax, wf, fmaf(Bx, hf, Cx));
        float iyp = fmaf(Ay, wf, fmaf(By, hf, Cy));
        float xf = floorf(ixp), yf = floorf(iyp);
        float wx1 = ixp - xf, wy1 = iyp - yf;
        // active iff xf in [0,1024] and yf in [0,1024]; then all 4 corners
        // are in-bounds of the padded buffer (border rows/cols are zero).
        bool act = (xf >= 0.f) & (xf <= (float)W) & (yf >= 0.f) & (yf <= (float)H);
        float idxf = fmaf(yf, (float)PITCH, xf);      // exact: < 2^24
        int idx = act ? (int)idxf : 0;                // safe address if inactive
        float pe = act ? p : 0.f;                     // zero contribution

        const float* q = in + idx;
        float v00 = q[0];
        float v01 = q[1];
        float v10 = q[PITCH];
        float v11 = q[PITCH + 1];
        float top = fmaf(wx1, v01 - v00, v00);
        float bot = fmaf(wx1, v11 - v10, v10);
        float val = fmaf(wy1, bot - top, top);
        acc = fmaf(pe, val, acc);
    }

    if (add_base) acc += base[0];
    out[h * dstPitch + w + dstOff] = acc;
}

extern "C" void kernel_launch(void* const* d_in, const int* in_sizes, int n_in,
                              void* d_out, int out_size, void* d_ws, size_t ws_size,
                              hipStream_t stream) {
    const float* canvas0 = (const float*)d_in[0];
    const float* theta   = (const float*)d_in[1];
    const float* probs   = (const float*)d_in[2];
    const float* base    = (const float*)d_in[3];
    float* out = (float*)d_out;

    float* bufA = (float*)d_ws;
    float* bufB = bufA + PAD_ELEMS;
    float* coef = bufB + PAD_ELEMS;

    // zero both padded buffers (borders must be 0; also kills 0xAA poison)
    hipMemsetAsync(d_ws, 0, (size_t)2 * PAD_ELEMS * sizeof(float), stream);

    setup_coef<<<1, 64, 0, stream>>>(theta, probs, coef);
    copy_in<<<(H * W) / 256, 256, 0, stream>>>(canvas0, bufA);

    dim3 block(256);
    dim3 grid(W / 16, H / 16);

    const float* cur = bufA;
    for (int i = 0; i < ITERS; ++i) {
        bool last = (i == ITERS - 1);
        float* dst = last ? out : ((i & 1) ? bufA : bufB);
        int dstPitch = last ? W : PITCH;
        int dstOff   = last ? 0 : (PITCH + 1);
        ifs_iter<<<grid, block, 0, stream>>>(cur, dst, coef, base,
                                             dstPitch, dstOff, last ? 1 : 0);
        cur = dst;
    }
}

// Round 4
// 444.342 us; speedup vs baseline: 1.8204x; 1.1976x over previous
//
#include <hip/hip_runtime.h>

// H=W=1024, T=16, 20 iterations. Intermediates in two zero-bordered padded
// buffers: PH x PITCH floats, pixel (h,w) at [(h+1)*PITCH + (w+1)]. Zero
// borders => all 4 bilinear corners of any in-range sample are loadable
// unconditionally (zeros padding is exact).
//
// R4 structure:
//  - 8x8 pixel patch per wave (fewer distinct rows per gather).
//  - per-16x16-tile 16-bit transform-active masks precomputed by setup_mask
//    (conservative bbox interval test) -> hot-loop skip is a SCALAR test,
//    removing ~26 VALU ops x 16 transforms per wave of uniform bbox math.
//  - transforms processed in PAIRS with branchless bodies: 8 independent
//    gathers in flight per wave (2x MLP vs one-transform-at-a-time).
constexpr int W = 1024;
constexpr int H = 1024;
constexpr int T = 16;
constexpr int ITERS = 20;
constexpr int PITCH = 1040;           // floats; 4160 B rows
constexpr int PH = H + 2;             // 1026 rows
constexpr int PAD_ELEMS = PH * PITCH;
constexpr int TILES_X = W / 16;       // 64
constexpr int TILES_Y = H / 16;       // 64

// coef per transform t: {p, Ax, Bx, Cxp, Ay, By, Cyp, 0}; Cxp/Cyp include the
// +1 pad shift, so ixp = Ax*w + Bx*h + Cxp is the PADDED x coordinate.
__global__ void setup_coef(const float* __restrict__ theta,
                           const float* __restrict__ probs,
                           float* __restrict__ coef) {
    int t = threadIdx.x;
    if (t >= T) return;
    float sum = 0.f;
    for (int i = 0; i < T; ++i) sum += probs[i];
    float p = probs[t] / sum;
    const float* th = theta + 6 * t;
    float a = th[0], b = th[1], c = th[2];
    float d = th[3], e = th[4], f = th[5];
    float Cx = a * ((1.0f - (float)W) * 0.5f)
             + b * ((1.0f - (float)H) * 0.5f)
             + (c + 1.0f) * ((float)W * 0.5f) - 0.5f;
    float Cy = d * ((1.0f - (float)W) * 0.5f)
             + e * ((1.0f - (float)H) * 0.5f)
             + (f + 1.0f) * ((float)H * 0.5f) - 0.5f;
    float* o = coef + 8 * t;
    o[0] = p;  o[1] = a;  o[2] = b;  o[3] = Cx + 1.0f;
    o[4] = d;  o[5] = e;  o[6] = Cy + 1.0f; o[7] = 0.f;
}

// One thread per 16x16 tile: bit t set iff transform t's sample bbox over the
// tile intersects the valid region (conservative => exact skip).
__global__ __launch_bounds__(256) void setup_mask(const float* __restrict__ coef,
                                                  unsigned* __restrict__ mask) {
    int tile = blockIdx.x * 256 + threadIdx.x;
    if (tile >= TILES_X * TILES_Y) return;
    int tx = tile & (TILES_X - 1), ty = tile / TILES_X;
    float w0 = (float)(tx * 16), w1 = w0 + 15.f;
    float h0 = (float)(ty * 16), h1 = h0 + 15.f;
    unsigned m = 0;
    for (int t = 0; t < T; ++t) {
        float Ax = coef[t * 8 + 1], Bx = coef[t * 8 + 2], Cx = coef[t * 8 + 3];
        float Ay = coef[t * 8 + 4], By = coef[t * 8 + 5], Cy = coef[t * 8 + 6];
        float ixmin = Cx + (Ax >= 0.f ? Ax * w0 : Ax * w1) + (Bx >= 0.f ? Bx * h0 : Bx * h1);
        float ixmax = Cx + (Ax >= 0.f ? Ax * w1 : Ax * w0) + (Bx >= 0.f ? Bx * h1 : Bx * h0);
        float iymin = Cy + (Ay >= 0.f ? Ay * w0 : Ay * w1) + (By >= 0.f ? By * h0 : By * h1);
        float iymax = Cy + (Ay >= 0.f ? Ay * w1 : Ay * w0) + (By >= 0.f ? By * h1 : By * h0);
        bool hit = !(ixmax <= 0.f || ixmin >= (float)(W + 1) ||
                     iymax <= 0.f || iymin >= (float)(H + 1));
        if (hit) m |= (1u << t);
    }
    mask[tile] = m;
}

__global__ __launch_bounds__(256) void copy_in(const float* __restrict__ src,
                                               float* __restrict__ dst) {
    int i = blockIdx.x * 256 + threadIdx.x;   // i in [0, H*W)
    int h = i >> 10, w = i & 1023;
    dst[(h + 1) * PITCH + (w + 1)] = src[i];
}

__global__ __launch_bounds__(256) void ifs_iter(const float* __restrict__ in,
                                                float* __restrict__ out,
                                                const float* __restrict__ coef,
                                                const unsigned* __restrict__ mask,
                                                const float* __restrict__ base,
                                                int dstPitch, int dstOff,
                                                int add_base) {
    __shared__ float sc[T * 8];
    if (threadIdx.x < T * 8) sc[threadIdx.x] = coef[threadIdx.x];
    __syncthreads();

    // scalar (wave-uniform) tile mask
    unsigned tmask = mask[blockIdx.y * TILES_X + blockIdx.x];

    // 8x8-per-wave mapping; 4 waves tile a 16x16 pixel block.
    int lane = threadIdx.x & 63;
    int wv   = threadIdx.x >> 6;
    int w = blockIdx.x * 16 + ((wv & 1) << 3) + (lane & 7);
    int h = blockIdx.y * 16 + ((wv >> 1) << 3) + (lane >> 3);
    float wf = (float)w, hf = (float)h;

    float acc = 0.f;

#pragma unroll
    for (int g = 0; g < T / 2; ++g) {
        if (((tmask >> (2 * g)) & 3u) == 0u) continue;   // scalar skip

        const float* c0 = sc + 16 * g;       // transform 2g
        const float* c1 = sc + 16 * g + 8;   // transform 2g+1
        float p0 = c0[0], Ax0 = c0[1], Bx0 = c0[2], Cx0 = c0[3];
        float Ay0 = c0[4], By0 = c0[5], Cy0 = c0[6];
        float p1 = c1[0], Ax1 = c1[1], Bx1 = c1[2], Cx1 = c1[3];
        float Ay1 = c1[4], By1 = c1[5], Cy1 = c1[6];

        float ix0 = fmaf(Ax0, wf, fmaf(Bx0, hf, Cx0));
        float iy0 = fmaf(Ay0, wf, fmaf(By0, hf, Cy0));
        float ix1 = fmaf(Ax1, wf, fmaf(Bx1, hf, Cx1));
        float iy1 = fmaf(Ay1, wf, fmaf(By1, hf, Cy1));
        float xf0 = floorf(ix0), yf0 = floorf(iy0);
        float xf1 = floorf(ix1), yf1 = floorf(iy1);
        bool act0 = (xf0 >= 0.f) & (xf0 <= (float)W) & (yf0 >= 0.f) & (yf0 <= (float)H);
        bool act1 = (xf1 >= 0.f) & (xf1 <= (float)W) & (yf1 >= 0.f) & (yf1 <= (float)H);
        int idx0 = act0 ? (int)fmaf(yf0, (float)PITCH, xf0) : 0;  // exact (<2^24)
        int idx1 = act1 ? (int)fmaf(yf1, (float)PITCH, xf1) : 0;
        float pe0 = act0 ? p0 : 0.f;
        float pe1 = act1 ? p1 : 0.f;

        // 8 independent gathers in flight
        const float* q0 = in + idx0;
        const float* q1 = in + idx1;
        float a00 = q0[0], a01 = q0[1], a10 = q0[PITCH], a11 = q0[PITCH + 1];
        float b00 = q1[0], b01 = q1[1], b10 = q1[PITCH], b11 = q1[PITCH + 1];

        float fx0 = ix0 - xf0, fy0 = iy0 - yf0;
        float fx1 = ix1 - xf1, fy1 = iy1 - yf1;
        float ta = fmaf(fx0, a01 - a00, a00);
        float ua = fmaf(fx0, a11 - a10, a10);
        float va = fmaf(fy0, ua - ta, ta);
        float tb = fmaf(fx1, b01 - b00, b00);
        float ub = fmaf(fx1, b11 - b10, b10);
        float vb = fmaf(fy1, ub - tb, tb);
        acc = fmaf(pe0, va, fmaf(pe1, vb, acc));
    }

    if (add_base) acc += base[0];
    out[h * dstPitch + w + dstOff] = acc;
}

extern "C" void kernel_launch(void* const* d_in, const int* in_sizes, int n_in,
                              void* d_out, int out_size, void* d_ws, size_t ws_size,
                              hipStream_t stream) {
    const float* canvas0 = (const float*)d_in[0];
    const float* theta   = (const float*)d_in[1];
    const float* probs   = (const float*)d_in[2];
    const float* base    = (const float*)d_in[3];
    float* out = (float*)d_out;

    float* bufA = (float*)d_ws;
    float* bufB = bufA + PAD_ELEMS;
    float* coef = bufB + PAD_ELEMS;
    unsigned* mask = (unsigned*)(coef + T * 8);

    // zero both padded buffers (borders must be 0; also kills 0xAA poison)
    hipMemsetAsync(d_ws, 0, (size_t)2 * PAD_ELEMS * sizeof(float), stream);

    setup_coef<<<1, 64, 0, stream>>>(theta, probs, coef);
    setup_mask<<<(TILES_X * TILES_Y + 255) / 256, 256, 0, stream>>>(coef, mask);
    copy_in<<<(H * W) / 256, 256, 0, stream>>>(canvas0, bufA);

    dim3 block(256);
    dim3 grid(TILES_X, TILES_Y);

    const float* cur = bufA;
    for (int i = 0; i < ITERS; ++i) {
        bool last = (i == ITERS - 1);
        float* dst = last ? out : ((i & 1) ? bufA : bufB);
        int dstPitch = last ? W : PITCH;
        int dstOff   = last ? 0 : (PITCH + 1);
        ifs_iter<<<grid, block, 0, stream>>>(cur, dst, coef, mask, base,
                                             dstPitch, dstOff, last ? 1 : 0);
        cur = dst;
    }
}

// Round 5
// 416.449 us; speedup vs baseline: 1.9423x; 1.0670x over previous
//
#include <hip/hip_runtime.h>

// H=W=1024, T=16, 20 iterations. Intermediates in two zero-bordered padded
// buffers: PH x PITCH floats, pixel (h,w) at [(h+1)*PITCH + (w+1)]. Zero
// borders => all 4 bilinear corners of any in-range sample are loadable
// unconditionally (zeros padding is exact).
//
// R5 structure:
//  - 8x8 pixel patch per wave; 4 waves -> 16x16 tile per block.
//  - per-tile 16-bit transform-active mask (conservative bbox, exact skip).
//  - block start: COMPACT active transforms' coefs into LDS (popc-indexed),
//    zero-pad to multiple of 4 -> branchless fully-active QUAD bodies,
//    wave-uniform trip count, no pair/quad granularity loss.
//  - corner pairs loaded as 8B vectors (aligned(4) ext vector) -> 2 gather
//    instructions per transform instead of 4; 8 gathers in flight per quad.
constexpr int W = 1024;
constexpr int H = 1024;
constexpr int T = 16;
constexpr int ITERS = 20;
constexpr int PITCH = 1040;           // floats; 4160 B rows
constexpr int PH = H + 2;             // 1026 rows
constexpr int PAD_ELEMS = PH * PITCH;
constexpr int TILES_X = W / 16;       // 64
constexpr int TILES_Y = H / 16;       // 64

typedef float f2 __attribute__((ext_vector_type(2), aligned(4)));

// coef per transform t: {p, Ax, Bx, Cxp, Ay, By, Cyp, 0}; Cxp/Cyp include the
// +1 pad shift, so ixp = Ax*w + Bx*h + Cxp is the PADDED x coordinate.
__global__ void setup_coef(const float* __restrict__ theta,
                           const float* __restrict__ probs,
                           float* __restrict__ coef) {
    int t = threadIdx.x;
    if (t >= T) return;
    float sum = 0.f;
    for (int i = 0; i < T; ++i) sum += probs[i];
    float p = probs[t] / sum;
    const float* th = theta + 6 * t;
    float a = th[0], b = th[1], c = th[2];
    float d = th[3], e = th[4], f = th[5];
    float Cx = a * ((1.0f - (float)W) * 0.5f)
             + b * ((1.0f - (float)H) * 0.5f)
             + (c + 1.0f) * ((float)W * 0.5f) - 0.5f;
    float Cy = d * ((1.0f - (float)W) * 0.5f)
             + e * ((1.0f - (float)H) * 0.5f)
             + (f + 1.0f) * ((float)H * 0.5f) - 0.5f;
    float* o = coef + 8 * t;
    o[0] = p;  o[1] = a;  o[2] = b;  o[3] = Cx + 1.0f;
    o[4] = d;  o[5] = e;  o[6] = Cy + 1.0f; o[7] = 0.f;
}

// One thread per 16x16 tile: bit t set iff transform t's sample bbox over the
// tile intersects the valid region (conservative => exact skip).
__global__ __launch_bounds__(256) void setup_mask(const float* __restrict__ coef,
                                                  unsigned* __restrict__ mask) {
    int tile = blockIdx.x * 256 + threadIdx.x;
    if (tile >= TILES_X * TILES_Y) return;
    int tx = tile & (TILES_X - 1), ty = tile / TILES_X;
    float w0 = (float)(tx * 16), w1 = w0 + 15.f;
    float h0 = (float)(ty * 16), h1 = h0 + 15.f;
    unsigned m = 0;
    for (int t = 0; t < T; ++t) {
        float Ax = coef[t * 8 + 1], Bx = coef[t * 8 + 2], Cx = coef[t * 8 + 3];
        float Ay = coef[t * 8 + 4], By = coef[t * 8 + 5], Cy = coef[t * 8 + 6];
        float ixmin = Cx + (Ax >= 0.f ? Ax * w0 : Ax * w1) + (Bx >= 0.f ? Bx * h0 : Bx * h1);
        float ixmax = Cx + (Ax >= 0.f ? Ax * w1 : Ax * w0) + (Bx >= 0.f ? Bx * h1 : Bx * h0);
        float iymin = Cy + (Ay >= 0.f ? Ay * w0 : Ay * w1) + (By >= 0.f ? By * h0 : By * h1);
        float iymax = Cy + (Ay >= 0.f ? Ay * w1 : Ay * w0) + (By >= 0.f ? By * h1 : By * h0);
        bool hit = !(ixmax <= 0.f || ixmin >= (float)(W + 1) ||
                     iymax <= 0.f || iymin >= (float)(H + 1));
        if (hit) m |= (1u << t);
    }
    mask[tile] = m;
}

__global__ __launch_bounds__(256) void copy_in(const float* __restrict__ src,
                                               float* __restrict__ dst) {
    int i = blockIdx.x * 256 + threadIdx.x;   // i in [0, H*W)
    int h = i >> 10, w = i & 1023;
    dst[(h + 1) * PITCH + (w + 1)] = src[i];
}

__global__ __launch_bounds__(256) void ifs_iter(const float* __restrict__ in,
                                                float* __restrict__ out,
                                                const float* __restrict__ coef,
                                                const unsigned* __restrict__ mask,
                                                const float* __restrict__ base,
                                                int dstPitch, int dstOff,
                                                int add_base) {
    // compacted coefs: up to 16 active + 3 zero-pad dummies
    __shared__ float sc[(T + 3) * 8];

    unsigned tmask = mask[blockIdx.y * TILES_X + blockIdx.x];
    int nact = __popc(tmask);
    int lid = threadIdx.x;

    if (lid < T * 8) {
        int t = lid >> 3;
        if (tmask & (1u << t)) {
            int pos = __popc(tmask & ((1u << t) - 1));
            sc[pos * 8 + (lid & 7)] = coef[lid];
        }
    }
    if (lid < 24) sc[nact * 8 + lid] = 0.f;  // dummy transforms: p=0 -> no-op
    __syncthreads();

    // 8x8-per-wave mapping; 4 waves tile a 16x16 pixel block.
    int lane = lid & 63;
    int wv   = lid >> 6;
    int w = blockIdx.x * 16 + ((wv & 1) << 3) + (lane & 7);
    int h = blockIdx.y * 16 + ((wv >> 1) << 3) + (lane >> 3);
    float wf = (float)w, hf = (float)h;

    float acc = 0.f;

    for (int g = 0; g < nact; g += 4) {   // wave-uniform trip count
        const float* c = sc + g * 8;
        float fx[4], fy[4], pe[4];
        int id0[4];
#pragma unroll
        for (int k = 0; k < 4; ++k) {
            const float* ck = c + k * 8;
            float p = ck[0], Ax = ck[1], Bx = ck[2], Cx = ck[3];
            float Ay = ck[4], By = ck[5], Cy = ck[6];
            float x = fmaf(Ax, wf, fmaf(Bx, hf, Cx));
            float y = fmaf(Ay, wf, fmaf(By, hf, Cy));
            float xf = floorf(x), yf = floorf(y);
            bool act = (xf >= 0.f) & (xf <= (float)W) & (yf >= 0.f) & (yf <= (float)H);
            id0[k] = act ? (int)fmaf(yf, (float)PITCH, xf) : 0;  // exact (<2^24)
            pe[k]  = act ? p : 0.f;
            fx[k] = x - xf;
            fy[k] = y - yf;
        }
        // 8 independent 8B gathers in flight (corner pairs are x-adjacent)
        f2 r0[4], r1[4];
#pragma unroll
        for (int k = 0; k < 4; ++k) {
            r0[k] = *(const f2*)(in + id0[k]);
            r1[k] = *(const f2*)(in + id0[k] + PITCH);
        }
#pragma unroll
        for (int k = 0; k < 4; ++k) {
            float top = fmaf(fx[k], r0[k].y - r0[k].x, r0[k].x);
            float bot = fmaf(fx[k], r1[k].y - r1[k].x, r1[k].x);
            acc = fmaf(pe[k], fmaf(fy[k], bot - top, top), acc);
        }
    }

    if (add_base) acc += base[0];
    out[h * dstPitch + w + dstOff] = acc;
}

extern "C" void kernel_launch(void* const* d_in, const int* in_sizes, int n_in,
                              void* d_out, int out_size, void* d_ws, size_t ws_size,
                              hipStream_t stream) {
    const float* canvas0 = (const float*)d_in[0];
    const float* theta   = (const float*)d_in[1];
    const float* probs   = (const float*)d_in[2];
    const float* base    = (const float*)d_in[3];
    float* out = (float*)d_out;

    float* bufA = (float*)d_ws;
    float* bufB = bufA + PAD_ELEMS;
    float* coef = bufB + PAD_ELEMS;
    unsigned* mask = (unsigned*)(coef + T * 8);

    // zero both padded buffers (borders must be 0; also kills 0xAA poison)
    hipMemsetAsync(d_ws, 0, (size_t)2 * PAD_ELEMS * sizeof(float), stream);

    setup_coef<<<1, 64, 0, stream>>>(theta, probs, coef);
    setup_mask<<<(TILES_X * TILES_Y + 255) / 256, 256, 0, stream>>>(coef, mask);
    copy_in<<<(H * W) / 256, 256, 0, stream>>>(canvas0, bufA);

    dim3 block(256);
    dim3 grid(TILES_X, TILES_Y);

    const float* cur = bufA;
    for (int i = 0; i < ITERS; ++i) {
        bool last = (i == ITERS - 1);
        float* dst = last ? out : ((i & 1) ? bufA : bufB);
        int dstPitch = last ? W : PITCH;
        int dstOff   = last ? 0 : (PITCH + 1);
        ifs_iter<<<grid, block, 0, stream>>>(cur, dst, coef, mask, base,
                                             dstPitch, dstOff, last ? 1 : 0);
        cur = dst;
    }
}